// Round 1
// baseline (16225.189 us; speedup 1.0000x reference)
//
#include <hip/hip_runtime.h>
#include <math.h>

#define LSEQ 4096
#define NFFT 8192
#define NF   512     // kept frequency bins (N_PARTIAL/2)
#define NH   768
#define NBH  6144    // 8*768

// ---------------- Kernel 1: trig tables cos/sin[f][n], f<512, n<4096 -------
__global__ void build_tables(float* __restrict__ cosT, float* __restrict__ sinT) {
    int idx = blockIdx.x * blockDim.x + threadIdx.x;   // f*4096 + n
    if (idx >= NF * LSEQ) return;
    int f = idx >> 12;
    int n = idx & (LSEQ - 1);
    int p = (f * n) & (NFFT - 1);                      // exact integer phase reduction
    float th = (float)p * (float)(2.0 * M_PI / (double)NFFT);
    float s, c;
    sincosf(th, &s, &c);
    cosT[idx] = c;
    sinT[idx] = s;
}

// ---------------- Kernel 2: K[h,f] = DFT of k at bins 0..511 ---------------
__global__ void kdft(const float* __restrict__ k,
                     const float* __restrict__ cosT, const float* __restrict__ sinT,
                     float* __restrict__ Kre, float* __restrict__ Kim) {
    int h = blockIdx.x >> 1;
    int f = ((blockIdx.x & 1) << 8) + threadIdx.x;     // 256 threads -> 2 blocks/h
    const float* kr = k + (size_t)h * LSEQ;
    const float* cr = cosT + (size_t)f * LSEQ;
    const float* sr = sinT + (size_t)f * LSEQ;
    float ac = 0.f, as = 0.f;
    for (int n = 0; n < LSEQ; ++n) {
        float kv = kr[n];
        ac = fmaf(kv, cr[n], ac);
        as = fmaf(kv, sr[n], as);
    }
    Kre[(size_t)h * NF + f] = ac;
    Kim[(size_t)h * NF + f] = -as;                     // e^{-i}: Im = -sum sin
}

// ------- Kernel 3: X[bh,f] forward DFT, multiply by K, pre-scale -----------
// A = s*(XreKre - XimKim), B = -s*(XreKim + XimKre), s=(f==0?1:2)/8192
__global__ void xdft_mul(const float* __restrict__ x,
                         const float* __restrict__ cosT, const float* __restrict__ sinT,
                         const float* __restrict__ Kre, const float* __restrict__ Kim,
                         float* __restrict__ A, float* __restrict__ B) {
    int bh = blockIdx.x >> 1;
    int f = ((blockIdx.x & 1) << 8) + threadIdx.x;
    int h = bh % NH;
    const float* xr = x + (size_t)bh * LSEQ;
    const float* cr = cosT + (size_t)f * LSEQ;
    const float* sr = sinT + (size_t)f * LSEQ;
    float ac = 0.f, as = 0.f;
    for (int n = 0; n < LSEQ; ++n) {
        float xv = xr[n];
        ac = fmaf(xv, cr[n], ac);
        as = fmaf(xv, sr[n], as);
    }
    float Xre = ac, Xim = -as;
    float kre = Kre[(size_t)h * NF + f];
    float kim = Kim[(size_t)h * NF + f];
    float s = (f == 0 ? 1.0f : 2.0f) * (1.0f / (float)NFFT);
    float yre = s * (Xre * kre - Xim * kim);
    float yim = s * (Xre * kim + Xim * kre);
    A[(size_t)bh * NF + f] = yre;
    B[(size_t)bh * NF + f] = -yim;                     // synth uses +sin with B
}

// ------- Kernel 4: y[bh,n] = sum_f A*cos[f][n] + B*sin[f][n] ---------------
__global__ void synth(const float* __restrict__ A, const float* __restrict__ B,
                      const float* __restrict__ cosT, const float* __restrict__ sinT,
                      float* __restrict__ y) {
    int bh = blockIdx.x >> 4;
    int n = ((blockIdx.x & 15) << 8) + threadIdx.x;    // 16 blocks x 256 = 4096
    const float* Ar = A + (size_t)bh * NF;
    const float* Br = B + (size_t)bh * NF;
    float acc = 0.f;
    for (int f = 0; f < NF; ++f) {
        acc = fmaf(Ar[f], cosT[(size_t)f * LSEQ + n], acc);
        acc = fmaf(Br[f], sinT[(size_t)f * LSEQ + n], acc);
    }
    y[(size_t)bh * LSEQ + n] = acc;
}

extern "C" void kernel_launch(void* const* d_in, const int* in_sizes, int n_in,
                              void* d_out, int out_size, void* d_ws, size_t ws_size,
                              hipStream_t stream) {
    const float* x = (const float*)d_in[0];   // [8,768,4096] fp32
    const float* k = (const float*)d_in[1];   // [768,4096]   fp32
    float* y = (float*)d_out;                 // [8,768,4096] fp32

    // Workspace layout (floats):
    float* ws = (float*)d_ws;
    float* cosT = ws;                               // 512*4096
    float* sinT = cosT + (size_t)NF * LSEQ;         // 512*4096
    float* Kre  = sinT + (size_t)NF * LSEQ;         // 768*512
    float* Kim  = Kre + (size_t)NH * NF;            // 768*512
    float* A    = Kim + (size_t)NH * NF;            // 6144*512
    float* B    = A + (size_t)NBH * NF;             // 6144*512
    // total ~45.1 MB

    const int blk = 256;
    hipLaunchKernelGGL(build_tables, dim3((NF * LSEQ) / blk), dim3(blk), 0, stream,
                       cosT, sinT);
    hipLaunchKernelGGL(kdft, dim3(NH * 2), dim3(blk), 0, stream,
                       k, cosT, sinT, Kre, Kim);
    hipLaunchKernelGGL(xdft_mul, dim3(NBH * 2), dim3(blk), 0, stream,
                       x, cosT, sinT, Kre, Kim, A, B);
    hipLaunchKernelGGL(synth, dim3(NBH * 16), dim3(blk), 0, stream,
                       A, B, cosT, sinT, y);
}

// Round 2
// 366.529 us; speedup vs baseline: 44.2671x; 44.2671x over previous
//
#include <hip/hip_runtime.h>
#include <math.h>

#define LSEQ 4096
#define NFFT 8192
#define NF   512     // kept frequency bins
#define NF2  1024    // 2*NF (cos/sin interleaved)
#define NH   768
#define NBH  6144    // 8*768
#define MROWS 6912   // NBH + NH (x rows + k rows share stage-A GEMM)

typedef __attribute__((ext_vector_type(8))) short short8;   // 8 bf16 (4 VGPRs)
typedef __attribute__((ext_vector_type(4))) float floatx4;  // MFMA accumulator

__device__ __forceinline__ unsigned short f2bf(float f) {
    unsigned int u = __float_as_uint(f);
    u += 0x7fff + ((u >> 16) & 1);       // round-to-nearest-even
    return (unsigned short)(u >> 16);
}

// -------- trig tables, bf16 ------------------------------------------------
// T1[f2][n], f2=0..1023, n=0..4095: even f2 -> cos(2*pi*f*n/8192), odd -> sin
__global__ void build_T1(unsigned short* __restrict__ T1) {
    int idx = blockIdx.x * blockDim.x + threadIdx.x;   // f2*4096 + n
    int f2 = idx >> 12;
    int n = idx & (LSEQ - 1);
    int f = f2 >> 1;
    int p = (f * n) & (NFFT - 1);
    float th = (float)p * (float)(2.0 * M_PI / (double)NFFT);
    float s, c;
    sincosf(th, &s, &c);
    T1[idx] = f2bf((f2 & 1) ? s : c);
}

// T2[n][f2] — transpose layout, rebuilt (coalesced writes) rather than transposed
__global__ void build_T2(unsigned short* __restrict__ T2) {
    int idx = blockIdx.x * blockDim.x + threadIdx.x;   // n*1024 + f2
    int n = idx >> 10;
    int f2 = idx & (NF2 - 1);
    int f = f2 >> 1;
    int p = (f * n) & (NFFT - 1);
    float th = (float)p * (float)(2.0 * M_PI / (double)NFFT);
    float s, c;
    sincosf(th, &s, &c);
    T2[idx] = f2bf((f2 & 1) ? s : c);
}

// -------- fp32 -> bf16 pack of [x ; k] into one [6912, 4096] matrix --------
__global__ void tobf16(const float* __restrict__ x, const float* __restrict__ kk,
                       unsigned short* __restrict__ o) {
    size_t e = ((size_t)blockIdx.x * 256 + threadIdx.x) * 4;
    const size_t XN = (size_t)NBH * LSEQ;
    const float* s = (e < XN) ? (x + e) : (kk + (e - XN));
    float4 v = *(const float4*)s;
    unsigned int lo = (unsigned int)f2bf(v.x) | ((unsigned int)f2bf(v.y) << 16);
    unsigned int hi = (unsigned int)f2bf(v.z) | ((unsigned int)f2bf(v.w) << 16);
    *(uint2*)(o + e) = make_uint2(lo, hi);
}

// -------- m97-style bf16 GEMM: C[M,N] = A[M,K] * B^T[N,K], fp32 out --------
__global__ __launch_bounds__(256) void gemm_bt(
    const unsigned short* __restrict__ A,   // [M,K] bf16
    const unsigned short* __restrict__ B,   // [N,K] bf16 (B transposed)
    float* __restrict__ C,                  // [M,N] fp32
    int M, int N, int K)
{
    __shared__ __align__(16) unsigned short As[128 * 32];
    __shared__ __align__(16) unsigned short Bs[128 * 32];
    const int t = threadIdx.x;
    const int w = t >> 6, l = t & 63;
    const int m0 = blockIdx.y * 128, n0 = blockIdx.x * 128;
    const int wm = (w >> 1) * 64, wn = (w & 1) * 64;
    const int lq = l >> 4;     // k-quad
    const int lr = l & 15;     // row/col within 16

    floatx4 acc[4][4];
#pragma unroll
    for (int i = 0; i < 4; ++i)
#pragma unroll
        for (int j = 0; j < 4; ++j)
            acc[i][j] = (floatx4){0.f, 0.f, 0.f, 0.f};

    const int q0 = t, q1 = t + 256;      // 16B staging chunks (512 per 8KB tile)
    const int r0 = q0 >> 2, e0 = (q0 & 3) * 8;
    const int r1 = q1 >> 2, e1 = (q1 & 3) * 8;

    for (int k0 = 0; k0 < K; k0 += 32) {
        const unsigned short* ga0 = A + (size_t)(m0 + r0) * K + k0 + e0;
        const unsigned short* ga1 = A + (size_t)(m0 + r1) * K + k0 + e1;
        const unsigned short* gb0 = B + (size_t)(n0 + r0) * K + k0 + e0;
        const unsigned short* gb1 = B + (size_t)(n0 + r1) * K + k0 + e1;
        __builtin_amdgcn_global_load_lds((const __attribute__((address_space(1))) void*)ga0,
            (__attribute__((address_space(3))) void*)(As + q0 * 8), 16, 0, 0);
        __builtin_amdgcn_global_load_lds((const __attribute__((address_space(1))) void*)ga1,
            (__attribute__((address_space(3))) void*)(As + q1 * 8), 16, 0, 0);
        __builtin_amdgcn_global_load_lds((const __attribute__((address_space(1))) void*)gb0,
            (__attribute__((address_space(3))) void*)(Bs + q0 * 8), 16, 0, 0);
        __builtin_amdgcn_global_load_lds((const __attribute__((address_space(1))) void*)gb1,
            (__attribute__((address_space(3))) void*)(Bs + q1 * 8), 16, 0, 0);
        __syncthreads();

        short8 af[4], bfv[4];
#pragma unroll
        for (int i = 0; i < 4; ++i)
            af[i] = *(const short8*)(As + (wm + 16 * i + lr) * 32 + lq * 8);
#pragma unroll
        for (int j = 0; j < 4; ++j)
            bfv[j] = *(const short8*)(Bs + (wn + 16 * j + lr) * 32 + lq * 8);
#pragma unroll
        for (int i = 0; i < 4; ++i)
#pragma unroll
            for (int j = 0; j < 4; ++j)
                acc[i][j] = __builtin_amdgcn_mfma_f32_16x16x32_bf16(af[i], bfv[j], acc[i][j], 0, 0, 0);
        __syncthreads();
    }

    // C/D layout: col = lane&15, row = (lane>>4)*4 + reg  [verified m89/m91]
#pragma unroll
    for (int i = 0; i < 4; ++i)
#pragma unroll
        for (int j = 0; j < 4; ++j)
#pragma unroll
            for (int r = 0; r < 4; ++r) {
                int row = m0 + wm + 16 * i + lq * 4 + r;
                int col = n0 + wn + 16 * j + lr;
                C[(size_t)row * N + col] = acc[i][j][r];
            }
}

// -------- complex multiply + irfft scaling -> bf16 AB[6144, 1024] ----------
// C1 rows 0..6143 = X DFT (P=sum x*cos, Q=sum x*sin interleaved), rows 6144.. = K DFT
__global__ void combine(const float* __restrict__ C1, unsigned short* __restrict__ AB) {
    int idx = blockIdx.x * blockDim.x + threadIdx.x;   // bh*512 + f
    int bh = idx >> 9;
    int f = idx & (NF - 1);
    int h = bh % NH;
    const float* xc = C1 + (size_t)bh * NF2 + 2 * f;
    const float* kc = C1 + (size_t)(NBH + h) * NF2 + 2 * f;
    float Xre = xc[0], Xim = -xc[1];
    float Kre = kc[0], Kim = -kc[1];
    float s = (f == 0 ? 1.0f : 2.0f) * (1.0f / (float)NFFT);
    float Av = s * (Xre * Kre - Xim * Kim);
    float Bv = -(s * (Xre * Kim + Xim * Kre));
    AB[(size_t)bh * NF2 + 2 * f]     = f2bf(Av);
    AB[(size_t)bh * NF2 + 2 * f + 1] = f2bf(Bv);
}

extern "C" void kernel_launch(void* const* d_in, const int* in_sizes, int n_in,
                              void* d_out, int out_size, void* d_ws, size_t ws_size,
                              hipStream_t stream) {
    const float* x = (const float*)d_in[0];   // [8,768,4096]
    const float* k = (const float*)d_in[1];   // [768,4096]
    float* y = (float*)d_out;

    // ws layout (29.4 MB total; 45.1 MB proven available in R1):
    unsigned short* T1 = (unsigned short*)d_ws;                 // [1024,4096] bf16, 8 MB
    unsigned short* T2 = T1 + (size_t)NF2 * LSEQ;               // [4096,1024] bf16, 8 MB
    unsigned short* AB = T2 + (size_t)LSEQ * NF2;               // [6144,1024] bf16, 12.6 MB

    // d_out doubles as scratch for stages before the final GEMM overwrites it:
    unsigned short* Abm = (unsigned short*)d_out;               // [6912,4096] bf16, 56.6 MB
    float* C1 = (float*)((char*)d_out + (size_t)MROWS * LSEQ * 2); // [6912,1024] f32, 28.3 MB

    const int blk = 256;
    hipLaunchKernelGGL(build_T1, dim3((NF2 * LSEQ) / blk), dim3(blk), 0, stream, T1);
    hipLaunchKernelGGL(build_T2, dim3((LSEQ * NF2) / blk), dim3(blk), 0, stream, T2);
    hipLaunchKernelGGL(tobf16, dim3((MROWS * LSEQ / 4) / blk), dim3(blk), 0, stream, x, k, Abm);
    // Stage A: [6912,4096] x [4096,1024] -> C1 (X and K spectra together)
    hipLaunchKernelGGL(gemm_bt, dim3(NF2 / 128, MROWS / 128), dim3(blk), 0, stream,
                       Abm, T1, C1, MROWS, NF2, LSEQ);
    hipLaunchKernelGGL(combine, dim3((NBH * NF) / blk), dim3(blk), 0, stream, C1, AB);
    // Stage B: [6144,1024] x [1024,4096] -> y
    hipLaunchKernelGGL(gemm_bt, dim3(LSEQ / 128, NBH / 128), dim3(blk), 0, stream,
                       AB, T2, y, NBH, LSEQ, NF2);
}

// Round 3
// 366.249 us; speedup vs baseline: 44.3010x; 1.0008x over previous
//
#include <hip/hip_runtime.h>
#include <math.h>

#define LSEQ 4096
#define NFFT 8192
#define NF   512     // kept frequency bins
#define NF2  1024    // 2*NF (cos/sin interleaved)
#define NH   768
#define NBH  6144    // 8*768
#define MROWS 6912   // NBH + NH (x rows + k rows share stage-A GEMM)
#define KSPLIT 2     // stage-A split-K factor (grid 432 -> 864 blocks)

typedef __attribute__((ext_vector_type(8))) short short8;   // 8 bf16 (4 VGPRs)
typedef __attribute__((ext_vector_type(4))) float floatx4;  // MFMA accumulator

__device__ __forceinline__ unsigned short f2bf(float f) {
    unsigned int u = __float_as_uint(f);
    u += 0x7fff + ((u >> 16) & 1);       // round-to-nearest-even
    return (unsigned short)(u >> 16);
}
__device__ __forceinline__ float bf2f(unsigned int u16) {
    return __uint_as_float(u16 << 16);
}

// -------- fused trig tables: T1[f2][n] and T2[n][f2], bf16 -----------------
// even f2 -> cos(2*pi*f*n/8192), odd -> sin;  T2 filled via LDS transpose
__global__ void build_tables(unsigned short* __restrict__ T1,
                             unsigned short* __restrict__ T2) {
    __shared__ unsigned short tile[64][66];   // pad 66: transpose-read conflict-free
    const int t = threadIdx.x;
    const int F0 = blockIdx.x * 64;           // f2 tile base (16 blocks)
    const int N0 = blockIdx.y * 64;           // n tile base (64 blocks)
#pragma unroll
    for (int i = 0; i < 16; ++i) {
        int r = (t >> 6) + i * 4;             // f2 within tile
        int c = t & 63;                       // n within tile
        int f2 = F0 + r, n = N0 + c;
        int f = f2 >> 1;
        int p = (f * n) & (NFFT - 1);
        float th = (float)p * (float)(2.0 * M_PI / (double)NFFT);
        float s, cc;
        sincosf(th, &s, &cc);
        unsigned short v = f2bf((f2 & 1) ? s : cc);
        T1[(size_t)f2 * LSEQ + n] = v;        // coalesced along n
        tile[r][c] = v;
    }
    __syncthreads();
#pragma unroll
    for (int i = 0; i < 16; ++i) {
        int r = (t >> 6) + i * 4;             // n within tile
        int c = t & 63;                       // f2 within tile
        T2[(size_t)(N0 + r) * NF2 + F0 + c] = tile[c][r];  // coalesced along f2
    }
}

// -------- fp32 -> bf16 pack of [x ; k] into one [6912, 4096] matrix --------
__global__ void tobf16(const float* __restrict__ x, const float* __restrict__ kk,
                       unsigned short* __restrict__ o) {
    size_t e = ((size_t)blockIdx.x * 256 + threadIdx.x) * 4;
    const size_t XN = (size_t)NBH * LSEQ;
    const float* s = (e < XN) ? (x + e) : (kk + (e - XN));
    float4 v = *(const float4*)s;
    unsigned int lo = (unsigned int)f2bf(v.x) | ((unsigned int)f2bf(v.y) << 16);
    unsigned int hi = (unsigned int)f2bf(v.z) | ((unsigned int)f2bf(v.w) << 16);
    *(uint2*)(o + e) = make_uint2(lo, hi);
}

// -------- stage A: split-K bf16 GEMM, bf16 partial outputs -----------------
// P[z][M,N] = A[M, z*K/2 : (z+1)*K/2] * B^T, bf16-rounded partials
__global__ __launch_bounds__(256) void gemm_a_splitk(
    const unsigned short* __restrict__ A,   // [M,K] bf16
    const unsigned short* __restrict__ B,   // [N,K] bf16 (transposed operand)
    unsigned short* __restrict__ P,         // [KSPLIT][M,N] bf16 partials
    int M, int N, int K)
{
    __shared__ __align__(16) unsigned short As[128 * 32];
    __shared__ __align__(16) unsigned short Bs[128 * 32];
    const int t = threadIdx.x;
    const int w = t >> 6, l = t & 63;
    const int m0 = blockIdx.y * 128, n0 = blockIdx.x * 128;
    const int wm = (w >> 1) * 64, wn = (w & 1) * 64;
    const int lq = l >> 4, lr = l & 15;
    const int kbeg = blockIdx.z * (K / KSPLIT);
    const int kend = kbeg + K / KSPLIT;

    floatx4 acc[4][4];
#pragma unroll
    for (int i = 0; i < 4; ++i)
#pragma unroll
        for (int j = 0; j < 4; ++j)
            acc[i][j] = (floatx4){0.f, 0.f, 0.f, 0.f};

    const int q0 = t, q1 = t + 256;
    const int r0 = q0 >> 2, e0 = (q0 & 3) * 8;
    const int r1 = q1 >> 2, e1 = (q1 & 3) * 8;

    for (int k0 = kbeg; k0 < kend; k0 += 32) {
        const unsigned short* ga0 = A + (size_t)(m0 + r0) * K + k0 + e0;
        const unsigned short* ga1 = A + (size_t)(m0 + r1) * K + k0 + e1;
        const unsigned short* gb0 = B + (size_t)(n0 + r0) * K + k0 + e0;
        const unsigned short* gb1 = B + (size_t)(n0 + r1) * K + k0 + e1;
        __builtin_amdgcn_global_load_lds((const __attribute__((address_space(1))) void*)ga0,
            (__attribute__((address_space(3))) void*)(As + q0 * 8), 16, 0, 0);
        __builtin_amdgcn_global_load_lds((const __attribute__((address_space(1))) void*)ga1,
            (__attribute__((address_space(3))) void*)(As + q1 * 8), 16, 0, 0);
        __builtin_amdgcn_global_load_lds((const __attribute__((address_space(1))) void*)gb0,
            (__attribute__((address_space(3))) void*)(Bs + q0 * 8), 16, 0, 0);
        __builtin_amdgcn_global_load_lds((const __attribute__((address_space(1))) void*)gb1,
            (__attribute__((address_space(3))) void*)(Bs + q1 * 8), 16, 0, 0);
        __syncthreads();

        short8 af[4], bfv[4];
#pragma unroll
        for (int i = 0; i < 4; ++i)
            af[i] = *(const short8*)(As + (wm + 16 * i + lr) * 32 + lq * 8);
#pragma unroll
        for (int j = 0; j < 4; ++j)
            bfv[j] = *(const short8*)(Bs + (wn + 16 * j + lr) * 32 + lq * 8);
#pragma unroll
        for (int i = 0; i < 4; ++i)
#pragma unroll
            for (int j = 0; j < 4; ++j)
                acc[i][j] = __builtin_amdgcn_mfma_f32_16x16x32_bf16(af[i], bfv[j], acc[i][j], 0, 0, 0);
        __syncthreads();
    }

    unsigned short* Pz = P + (size_t)blockIdx.z * M * N;
#pragma unroll
    for (int i = 0; i < 4; ++i)
#pragma unroll
        for (int j = 0; j < 4; ++j)
#pragma unroll
            for (int r = 0; r < 4; ++r) {
                int row = m0 + wm + 16 * i + lq * 4 + r;
                int col = n0 + wn + 16 * j + lr;
                Pz[(size_t)row * N + col] = f2bf(acc[i][j][r]);
            }
}

// -------- stage B: bf16 GEMM, fp32 output (m97 structure, unchanged) -------
__global__ __launch_bounds__(256) void gemm_bt(
    const unsigned short* __restrict__ A,
    const unsigned short* __restrict__ B,
    float* __restrict__ C,
    int M, int N, int K)
{
    __shared__ __align__(16) unsigned short As[128 * 32];
    __shared__ __align__(16) unsigned short Bs[128 * 32];
    const int t = threadIdx.x;
    const int w = t >> 6, l = t & 63;
    const int m0 = blockIdx.y * 128, n0 = blockIdx.x * 128;
    const int wm = (w >> 1) * 64, wn = (w & 1) * 64;
    const int lq = l >> 4, lr = l & 15;

    floatx4 acc[4][4];
#pragma unroll
    for (int i = 0; i < 4; ++i)
#pragma unroll
        for (int j = 0; j < 4; ++j)
            acc[i][j] = (floatx4){0.f, 0.f, 0.f, 0.f};

    const int q0 = t, q1 = t + 256;
    const int r0 = q0 >> 2, e0 = (q0 & 3) * 8;
    const int r1 = q1 >> 2, e1 = (q1 & 3) * 8;

    for (int k0 = 0; k0 < K; k0 += 32) {
        const unsigned short* ga0 = A + (size_t)(m0 + r0) * K + k0 + e0;
        const unsigned short* ga1 = A + (size_t)(m0 + r1) * K + k0 + e1;
        const unsigned short* gb0 = B + (size_t)(n0 + r0) * K + k0 + e0;
        const unsigned short* gb1 = B + (size_t)(n0 + r1) * K + k0 + e1;
        __builtin_amdgcn_global_load_lds((const __attribute__((address_space(1))) void*)ga0,
            (__attribute__((address_space(3))) void*)(As + q0 * 8), 16, 0, 0);
        __builtin_amdgcn_global_load_lds((const __attribute__((address_space(1))) void*)ga1,
            (__attribute__((address_space(3))) void*)(As + q1 * 8), 16, 0, 0);
        __builtin_amdgcn_global_load_lds((const __attribute__((address_space(1))) void*)gb0,
            (__attribute__((address_space(3))) void*)(Bs + q0 * 8), 16, 0, 0);
        __builtin_amdgcn_global_load_lds((const __attribute__((address_space(1))) void*)gb1,
            (__attribute__((address_space(3))) void*)(Bs + q1 * 8), 16, 0, 0);
        __syncthreads();

        short8 af[4], bfv[4];
#pragma unroll
        for (int i = 0; i < 4; ++i)
            af[i] = *(const short8*)(As + (wm + 16 * i + lr) * 32 + lq * 8);
#pragma unroll
        for (int j = 0; j < 4; ++j)
            bfv[j] = *(const short8*)(Bs + (wn + 16 * j + lr) * 32 + lq * 8);
#pragma unroll
        for (int i = 0; i < 4; ++i)
#pragma unroll
            for (int j = 0; j < 4; ++j)
                acc[i][j] = __builtin_amdgcn_mfma_f32_16x16x32_bf16(af[i], bfv[j], acc[i][j], 0, 0, 0);
        __syncthreads();
    }

#pragma unroll
    for (int i = 0; i < 4; ++i)
#pragma unroll
        for (int j = 0; j < 4; ++j)
#pragma unroll
            for (int r = 0; r < 4; ++r) {
                int row = m0 + wm + 16 * i + lq * 4 + r;
                int col = n0 + wn + 16 * j + lr;
                C[(size_t)row * N + col] = acc[i][j][r];
            }
}

// -------- combine: sum split-K partials, complex multiply, scale -> AB -----
__global__ void combine(const unsigned short* __restrict__ P,   // [2][6912,1024] bf16
                        unsigned short* __restrict__ AB) {      // [6144,1024] bf16
    int idx = blockIdx.x * blockDim.x + threadIdx.x;   // bh*512 + f
    int bh = idx >> 9;
    int f = idx & (NF - 1);
    int h = bh % NH;
    const size_t PS = (size_t)MROWS * NF2;
    unsigned int x0 = *(const unsigned int*)(P + (size_t)bh * NF2 + 2 * f);
    unsigned int x1 = *(const unsigned int*)(P + PS + (size_t)bh * NF2 + 2 * f);
    unsigned int k0 = *(const unsigned int*)(P + (size_t)(NBH + h) * NF2 + 2 * f);
    unsigned int k1 = *(const unsigned int*)(P + PS + (size_t)(NBH + h) * NF2 + 2 * f);
    float Xre = bf2f(x0 & 0xffff) + bf2f(x1 & 0xffff);
    float Xim = -(bf2f(x0 >> 16) + bf2f(x1 >> 16));
    float Kre = bf2f(k0 & 0xffff) + bf2f(k1 & 0xffff);
    float Kim = -(bf2f(k0 >> 16) + bf2f(k1 >> 16));
    float s = (f == 0 ? 1.0f : 2.0f) * (1.0f / (float)NFFT);
    float Av = s * (Xre * Kre - Xim * Kim);
    float Bv = -(s * (Xre * Kim + Xim * Kre));
    unsigned int packed = (unsigned int)f2bf(Av) | ((unsigned int)f2bf(Bv) << 16);
    *(unsigned int*)(AB + (size_t)bh * NF2 + 2 * f) = packed;
}

extern "C" void kernel_launch(void* const* d_in, const int* in_sizes, int n_in,
                              void* d_out, int out_size, void* d_ws, size_t ws_size,
                              hipStream_t stream) {
    const float* x = (const float*)d_in[0];   // [8,768,4096]
    const float* k = (const float*)d_in[1];   // [768,4096]
    float* y = (float*)d_out;

    // ws layout (29.4 MB; 45.1 MB proven available in R1):
    unsigned short* T1 = (unsigned short*)d_ws;                 // [1024,4096] bf16
    unsigned short* T2 = T1 + (size_t)NF2 * LSEQ;               // [4096,1024] bf16
    unsigned short* AB = T2 + (size_t)LSEQ * NF2;               // [6144,1024] bf16

    // d_out doubles as scratch (85 MB of 100.66 MB) until stage B overwrites:
    unsigned short* Abm = (unsigned short*)d_out;               // [6912,4096] bf16, 56.6 MB
    unsigned short* P = Abm + (size_t)MROWS * LSEQ;             // [2][6912,1024] bf16, 28.3 MB

    const int blk = 256;
    hipLaunchKernelGGL(build_tables, dim3(NF2 / 64, LSEQ / 64), dim3(blk), 0, stream, T1, T2);
    hipLaunchKernelGGL(tobf16, dim3((MROWS * LSEQ / 4) / blk), dim3(blk), 0, stream, x, k, Abm);
    // Stage A: split-K=2, [6912,4096] x [4096,1024] -> bf16 partials (grid 864)
    hipLaunchKernelGGL(gemm_a_splitk, dim3(NF2 / 128, MROWS / 128, KSPLIT), dim3(blk), 0, stream,
                       Abm, T1, P, MROWS, NF2, LSEQ);
    hipLaunchKernelGGL(combine, dim3((NBH * NF) / blk), dim3(blk), 0, stream, P, AB);
    // Stage B: [6144,1024] x [1024,4096] -> y (grid 1536)
    hipLaunchKernelGGL(gemm_bt, dim3(LSEQ / 128, NBH / 128), dim3(blk), 0, stream,
                       AB, T2, y, NBH, LSEQ, NF2);
}

// Round 4
// 339.704 us; speedup vs baseline: 47.7627x; 1.0781x over previous
//
#include <hip/hip_runtime.h>
#include <math.h>

#define LSEQ 4096
#define NFFT 8192
#define NF   512     // kept frequency bins
#define NF2  1024    // 2*NF (cos/sin interleaved)
#define NH   768
#define NBH  6144    // 8*768
#define MROWS 6912   // NBH + NH (x rows + k rows share stage-A GEMM)

typedef __attribute__((ext_vector_type(8))) short short8;   // 8 bf16 (4 VGPRs)
typedef __attribute__((ext_vector_type(4))) float floatx4;  // MFMA accumulator

__device__ __forceinline__ unsigned short f2bf(float f) {
    unsigned int u = __float_as_uint(f);
    u += 0x7fff + ((u >> 16) & 1);       // round-to-nearest-even
    return (unsigned short)(u >> 16);
}

// -------- fused trig tables: T1[f2][n] and T2[n][f2], bf16 -----------------
__global__ void build_tables(unsigned short* __restrict__ T1,
                             unsigned short* __restrict__ T2) {
    __shared__ unsigned short tile[64][66];   // pad 66: transpose-read conflict-free
    const int t = threadIdx.x;
    const int F0 = blockIdx.x * 64;
    const int N0 = blockIdx.y * 64;
#pragma unroll
    for (int i = 0; i < 16; ++i) {
        int r = (t >> 6) + i * 4;
        int c = t & 63;
        int f2 = F0 + r, n = N0 + c;
        int f = f2 >> 1;
        int p = (f * n) & (NFFT - 1);
        float th = (float)p * (float)(2.0 * M_PI / (double)NFFT);
        float s, cc;
        sincosf(th, &s, &cc);
        unsigned short v = f2bf((f2 & 1) ? s : cc);
        T1[(size_t)f2 * LSEQ + n] = v;
        tile[r][c] = v;
    }
    __syncthreads();
#pragma unroll
    for (int i = 0; i < 16; ++i) {
        int r = (t >> 6) + i * 4;
        int c = t & 63;
        T2[(size_t)(N0 + r) * NF2 + F0 + c] = tile[c][r];
    }
}

// -------- fp32 -> bf16 pack of [x ; k] into one [6912, 4096] matrix --------
__global__ void tobf16(const float* __restrict__ x, const float* __restrict__ kk,
                       unsigned short* __restrict__ o) {
    size_t e = ((size_t)blockIdx.x * 256 + threadIdx.x) * 4;
    const size_t XN = (size_t)NBH * LSEQ;
    const float* s = (e < XN) ? (x + e) : (kk + (e - XN));
    float4 v = *(const float4*)s;
    unsigned int lo = (unsigned int)f2bf(v.x) | ((unsigned int)f2bf(v.y) << 16);
    unsigned int hi = (unsigned int)f2bf(v.z) | ((unsigned int)f2bf(v.w) << 16);
    *(uint2*)(o + e) = make_uint2(lo, hi);
}

// -------- pipelined bf16 GEMM: C[M,N] = A[M,K] * B^T[N,K], fp32 out --------
// Register-prefetch + LDS double-buffer, one barrier per K-iter:
//   loads for tile k+1 issue BEFORE tile k's MFMAs (vmcnt wait lands at the
//   ds_write to the other buffer), so global latency overlaps the MFMA phase
//   instead of sitting in the vmcnt(0)+s_barrier drain (R2/R3: ~1230 cyc/iter
//   vs ~310 cyc MFMA floor).
__global__ __launch_bounds__(256) void gemm_bt(
    const unsigned short* __restrict__ A,   // [M,K] bf16
    const unsigned short* __restrict__ B,   // [N,K] bf16 (transposed operand)
    float* __restrict__ C,                  // [M,N] fp32
    int M, int N, int K)
{
    __shared__ __align__(16) unsigned short As[2][128 * 32];
    __shared__ __align__(16) unsigned short Bs[2][128 * 32];
    const int t = threadIdx.x;
    const int w = t >> 6, l = t & 63;
    const int m0 = blockIdx.y * 128, n0 = blockIdx.x * 128;
    const int wm = (w >> 1) * 64, wn = (w & 1) * 64;
    const int lq = l >> 4, lr = l & 15;

    floatx4 acc[4][4];
#pragma unroll
    for (int i = 0; i < 4; ++i)
#pragma unroll
        for (int j = 0; j < 4; ++j)
            acc[i][j] = (floatx4){0.f, 0.f, 0.f, 0.f};

    // staging: 2 x 16B chunks per operand per thread (8 KB tile / 256 thr)
    const int q0 = t, q1 = t + 256;
    const int r0 = q0 >> 2, e0 = (q0 & 3) * 8;
    const int r1 = q1 >> 2, e1 = (q1 & 3) * 8;
    const unsigned short* pa0 = A + (size_t)(m0 + r0) * K + e0;
    const unsigned short* pa1 = A + (size_t)(m0 + r1) * K + e1;
    const unsigned short* pb0 = B + (size_t)(n0 + r0) * K + e0;
    const unsigned short* pb1 = B + (size_t)(n0 + r1) * K + e1;

    // prologue: tile 0 -> regs -> LDS buf0
    uint4 ra0 = *(const uint4*)pa0;
    uint4 ra1 = *(const uint4*)pa1;
    uint4 rb0 = *(const uint4*)pb0;
    uint4 rb1 = *(const uint4*)pb1;
    *(uint4*)(As[0] + q0 * 8) = ra0;
    *(uint4*)(As[0] + q1 * 8) = ra1;
    *(uint4*)(Bs[0] + q0 * 8) = rb0;
    *(uint4*)(Bs[0] + q1 * 8) = rb1;
    __syncthreads();

    int cur = 0;
    for (int k0 = 32; k0 < K; k0 += 32) {
        // issue next tile's global loads first (overlap with MFMAs below)
        ra0 = *(const uint4*)(pa0 + k0);
        ra1 = *(const uint4*)(pa1 + k0);
        rb0 = *(const uint4*)(pb0 + k0);
        rb1 = *(const uint4*)(pb1 + k0);

        short8 af[4], bfv[4];
#pragma unroll
        for (int i = 0; i < 4; ++i)
            af[i] = *(const short8*)(As[cur] + (wm + 16 * i + lr) * 32 + lq * 8);
#pragma unroll
        for (int j = 0; j < 4; ++j)
            bfv[j] = *(const short8*)(Bs[cur] + (wn + 16 * j + lr) * 32 + lq * 8);
#pragma unroll
        for (int i = 0; i < 4; ++i)
#pragma unroll
            for (int j = 0; j < 4; ++j)
                acc[i][j] = __builtin_amdgcn_mfma_f32_16x16x32_bf16(af[i], bfv[j], acc[i][j], 0, 0, 0);

        const int nxt = cur ^ 1;
        *(uint4*)(As[nxt] + q0 * 8) = ra0;   // vmcnt wait lands here, post-MFMA
        *(uint4*)(As[nxt] + q1 * 8) = ra1;
        *(uint4*)(Bs[nxt] + q0 * 8) = rb0;
        *(uint4*)(Bs[nxt] + q1 * 8) = rb1;
        __syncthreads();
        cur = nxt;
    }

    // last tile
    {
        short8 af[4], bfv[4];
#pragma unroll
        for (int i = 0; i < 4; ++i)
            af[i] = *(const short8*)(As[cur] + (wm + 16 * i + lr) * 32 + lq * 8);
#pragma unroll
        for (int j = 0; j < 4; ++j)
            bfv[j] = *(const short8*)(Bs[cur] + (wn + 16 * j + lr) * 32 + lq * 8);
#pragma unroll
        for (int i = 0; i < 4; ++i)
#pragma unroll
            for (int j = 0; j < 4; ++j)
                acc[i][j] = __builtin_amdgcn_mfma_f32_16x16x32_bf16(af[i], bfv[j], acc[i][j], 0, 0, 0);
    }

    // C/D layout: col = lane&15, row = (lane>>4)*4 + reg  [verified m89/m91]
#pragma unroll
    for (int i = 0; i < 4; ++i)
#pragma unroll
        for (int j = 0; j < 4; ++j)
#pragma unroll
            for (int r = 0; r < 4; ++r) {
                int row = m0 + wm + 16 * i + lq * 4 + r;
                int col = n0 + wn + 16 * j + lr;
                C[(size_t)row * N + col] = acc[i][j][r];
            }
}

// -------- combine: complex multiply + irfft scaling -> bf16 AB -------------
__global__ void combine(const float* __restrict__ C1, unsigned short* __restrict__ AB) {
    int idx = blockIdx.x * blockDim.x + threadIdx.x;   // bh*512 + f
    int bh = idx >> 9;
    int f = idx & (NF - 1);
    int h = bh % NH;
    const float* xc = C1 + (size_t)bh * NF2 + 2 * f;
    const float* kc = C1 + (size_t)(NBH + h) * NF2 + 2 * f;
    float Xre = xc[0], Xim = -xc[1];
    float Kre = kc[0], Kim = -kc[1];
    float s = (f == 0 ? 1.0f : 2.0f) * (1.0f / (float)NFFT);
    float Av = s * (Xre * Kre - Xim * Kim);
    float Bv = -(s * (Xre * Kim + Xim * Kre));
    unsigned int packed = (unsigned int)f2bf(Av) | ((unsigned int)f2bf(Bv) << 16);
    *(unsigned int*)(AB + (size_t)bh * NF2 + 2 * f) = packed;
}

extern "C" void kernel_launch(void* const* d_in, const int* in_sizes, int n_in,
                              void* d_out, int out_size, void* d_ws, size_t ws_size,
                              hipStream_t stream) {
    const float* x = (const float*)d_in[0];   // [8,768,4096]
    const float* k = (const float*)d_in[1];   // [768,4096]
    float* y = (float*)d_out;

    // ws layout (28.6 MB; 45.1 MB proven available in R1):
    unsigned short* T1 = (unsigned short*)d_ws;                 // [1024,4096] bf16
    unsigned short* T2 = T1 + (size_t)NF2 * LSEQ;               // [4096,1024] bf16
    unsigned short* AB = T2 + (size_t)LSEQ * NF2;               // [6144,1024] bf16

    // d_out doubles as scratch (85 MB of 100.66 MB) until stage B overwrites:
    unsigned short* Abm = (unsigned short*)d_out;               // [6912,4096] bf16, 56.6 MB
    float* C1 = (float*)((char*)d_out + (size_t)MROWS * LSEQ * 2); // [6912,1024] f32, 28.3 MB

    const int blk = 256;
    hipLaunchKernelGGL(build_tables, dim3(NF2 / 64, LSEQ / 64), dim3(blk), 0, stream, T1, T2);
    hipLaunchKernelGGL(tobf16, dim3((MROWS * LSEQ / 4) / blk), dim3(blk), 0, stream, x, k, Abm);
    // Stage A: [6912,4096] x [4096,1024] -> C1 (X and K spectra together)
    hipLaunchKernelGGL(gemm_bt, dim3(NF2 / 128, MROWS / 128), dim3(blk), 0, stream,
                       Abm, T1, C1, MROWS, NF2, LSEQ);
    hipLaunchKernelGGL(combine, dim3((NBH * NF) / blk), dim3(blk), 0, stream, C1, AB);
    // Stage B: [6144,1024] x [1024,4096] -> y
    hipLaunchKernelGGL(gemm_bt, dim3(LSEQ / 128, NBH / 128), dim3(blk), 0, stream,
                       AB, T2, y, NBH, LSEQ, NF2);
}